// Round 10
// baseline (589.991 us; speedup 1.0000x reference)
//
#include <hip/hip_runtime.h>
#include <math.h>

typedef __attribute__((ext_vector_type(4))) float f4;
typedef __attribute__((ext_vector_type(8))) _Float16 f16x8;
typedef __attribute__((ext_vector_type(8))) short bf16x8;
typedef __attribute__((ext_vector_type(4))) unsigned short u16x4;
typedef unsigned int u32;
typedef unsigned short u16;

#define DIMC  512
#define NITEM 2048
#define TK    10
#define WSP   (NITEM * DIMC)          // mp plane stride (u16) = 1,048,576
#define XWSP  (32 * DIMC * 1024)      // x  plane stride (u16) = 16,777,216
#define QWS_OFF (3 * WSP)             // q planes start after 3 mp planes

// ---------------- main kernel geometry ----------------
#define TPB    512                    // 8 waves: 4 item-groups x 2 px-groups
#define PXB    64
#define RIT    256
#define NRND   8
#define NSLICE 16

// ---------------- LDS (direct kernel): S overlay only ----------------
#define SSTR   66
// merge overlay (float indices from base 0)
#define MV_F 0
#define MI_F 5120
#define MM_F 10240
#define MS_F 10752
#define WB_F 11264
#define IB_F 11904

// fallback kernel LDS layout (r9)
#define QB_SZ  12288
#define Q_PL   4096
#define LDS_BYTES 67584
#define KSWZ(i) (((i) ^ ((i) >> 2)) & 3)

union h16 { _Float16 h; u16 u; };

__device__ __forceinline__ u32 bf16_rne(float f) {
    u32 u = __float_as_uint(f);
    return (u + 0x7fffu + ((u >> 16) & 1u)) >> 16;
}

// mixed split: f = fp16(f) + residual; planes {fp16(f), bf16(f), bf16(res)}.
// m*q ~= h(m)h(q) + b(m)b(qres) + b(mres)b(q)  (all true-scale -> one acc)
__device__ __forceinline__ void split3(float f, u16& ph, u16& pb, u16& pr) {
    h16 a; a.h = (_Float16)f;
    float f0 = (float)a.h;
    ph = a.u;
    pb = (u16)bf16_rne(f);
    pr = (u16)bf16_rne(f - f0);
}

// mempool fp32 -> 3 planes, fragment-major (r9-verified layout):
// addr = plane*WSP + (i>>4)*8192 + s*512 + (lh*16 + (i&15))*8 + pair*4 + j
// for k = s*32 + pair*16 + lh*4 + j.
__global__ __launch_bounds__(256)
void preconv_kernel(const float* __restrict__ mp, u16* __restrict__ ws)
{
    int idx = (blockIdx.x * 256 + threadIdx.x) * 4;
    int i  = idx >> 9;
    int k0 = idx & 511;
    f4 v = *(const f4*)(mp + (size_t)i * 512 + k0);
    int s  = k0 >> 5, kl = k0 & 31;
    int lh = (kl >> 2) & 3, pair = kl >> 4;
    u16x4 pH, pB, pR;
#pragma unroll
    for (int e = 0; e < 4; ++e) {
        u16 h, b, r; split3(v[e], h, b, r);
        pH[e] = h; pB[e] = b; pR[e] = r;
    }
    size_t base = (size_t)(i >> 4) * 8192 + (size_t)s * 512
                + (size_t)(lh * 16 + (i & 15)) * 8 + pair * 4;
    *(u16x4*)(ws + 0 * WSP + base) = pH;
    *(u16x4*)(ws + 1 * WSP + base) = pB;
    *(u16x4*)(ws + 2 * WSP + base) = pR;
}

// x fp32 -> 3 planes at QWS_OFF, SAME fragment-major layout keyed by global
// px-group G = img*64 + (px>>4):
//   addr = QWS_OFF + p*XWSP + G*8192 + s*512 + (lh*16 + (px&15))*8 + pair*4 + j
// for channel c = s*32 + pair*16 + lh*4 + j.  One-time conversion removes the
// 8x per-round q re-conversion and all q LDS staging from the main kernel.
__global__ __launch_bounds__(256)
void preconv_x_kernel(const float* __restrict__ x0, const float* __restrict__ x1,
                      u16* __restrict__ ws)
{
    int T   = blockIdx.x * 256 + threadIdx.x;   // [0, 4,194,304)
    int px  = T & 1023;
    int c4  = (T >> 10) & 127;                  // c>>2
    int img = T >> 17;                          // 0..31
    const float* x = (img < 16) ? x0 : x1;
    const float* src = x + ((size_t)(img & 15) * 512 + (size_t)c4 * 4) * 1024 + px;
    int s = c4 >> 3, pair = (c4 >> 2) & 1, lh = c4 & 3;
    u16x4 pH, pB, pR;
#pragma unroll
    for (int j = 0; j < 4; ++j) {
        u16 h, b, r; split3(src[(size_t)j * 1024], h, b, r);
        pH[j] = h; pB[j] = b; pR[j] = r;
    }
    size_t base = (size_t)QWS_OFF
                + (size_t)(img * 64 + (px >> 4)) * 8192 + (size_t)s * 512
                + (size_t)((lh * 16 + (px & 15)) << 3) + pair * 4;
    *(u16x4*)(ws + base + 0 * (size_t)XWSP) = pH;
    *(u16x4*)(ws + base + 1 * (size_t)XWSP) = pB;
    *(u16x4*)(ws + base + 2 * (size_t)XWSP) = pR;
}

// -------- main kernel: barrier-free, LDS-free, VALU-free K-loop --------
__global__ __launch_bounds__(TPB, 4)
void memorize_direct(const float* __restrict__ mp, const u16* __restrict__ ws,
                     float* __restrict__ out)
{
    __shared__ float ldsf[16896];   // 67,584 B: S overlay + merge arrays

    const int t    = threadIdx.x;
    const int lane = t & 63;
    const int w    = t >> 6;
    const int blk  = blockIdx.x;        // 0..511
    const int img  = blk >> 4;          // 0..31
    const int n0   = (blk & 15) * PXB;

    float* ob = out + (img < 16 ? (size_t)0 : (size_t)16 * DIMC * 1024)
                    + (size_t)(img & 15) * (DIMC * 1024);

    const int l15 = lane & 15;
    const int lh  = lane >> 4;
    const int ig  = w >> 1;             // item group: items ig*64..+63
    const int pg  = w & 1;              // px group:   px pg*32..+31

    const int qp = t & 63;
    const int g  = t >> 6;

    float tv[TK]; int tix[TK];
#pragma unroll
    for (int q = 0; q < TK; ++q) { tv[q] = -INFINITY; tix[q] = 0x7fffffff; }
    float rm = -INFINITY, rs = 0.0f;

    // A-side base (mp planes), r9-verified addressing
    const u16* aw = ws + (size_t)lane * 8 + (size_t)(ig * 4) * 8192;
    // B-side base (q planes)
    const int G0 = img * 64 + (blk & 15) * 4 + pg * 2;
    const u16* bw = ws + (size_t)QWS_OFF + (size_t)G0 * 8192 + (size_t)lane * 8;

#define ALOAD(IT, S)                                                           \
    {                                                                          \
        const u16* ap = ar + ((size_t)(IT) << 13) + ((S) << 9);                \
        aH[IT] = *(const f16x8*) (ap + 0 * WSP);                               \
        aB[IT] = *(const bf16x8*)(ap + 1 * WSP);                               \
        aR[IT] = *(const bf16x8*)(ap + 2 * WSP);                               \
    }

#pragma unroll 1
    for (int r = 0; r < NRND; ++r) {
        const u16* ar = aw + ((size_t)r << 17);
        f4 acc[4][2];
#pragma unroll
        for (int it = 0; it < 4; ++it)
#pragma unroll
            for (int pt = 0; pt < 2; ++pt) acc[it][pt] = (f4){0.f, 0.f, 0.f, 0.f};

#pragma unroll 1
        for (int s = 0; s < NSLICE; ++s) {
            // B frags direct from ws (L1/L2-hot, contiguous 1 KB per wave)
            f16x8 qH[2]; bf16x8 qB[2], qR[2];
#pragma unroll
            for (int pt = 0; pt < 2; ++pt) {
                const u16* bp = bw + ((size_t)pt << 13) + ((size_t)s << 9);
                qH[pt] = *(const f16x8*) (bp + 0 * (size_t)XWSP);
                qB[pt] = *(const bf16x8*)(bp + 1 * (size_t)XWSP);
                qR[pt] = *(const bf16x8*)(bp + 2 * (size_t)XWSP);
            }
            // A frags, staggered with MFMAs
            f16x8 aH[4]; bf16x8 aB[4], aR[4];
            ALOAD(0, s)
            ALOAD(1, s)
#pragma unroll
            for (int it = 0; it < 4; ++it) {
                if (it < 2) ALOAD(it + 2, s)
#pragma unroll
                for (int pt = 0; pt < 2; ++pt) {
                    f4 c = acc[it][pt];
                    c = __builtin_amdgcn_mfma_f32_16x16x32_f16 (aH[it], qH[pt], c, 0, 0, 0);
                    c = __builtin_amdgcn_mfma_f32_16x16x32_bf16(aB[it], qR[pt], c, 0, 0, 0);
                    c = __builtin_amdgcn_mfma_f32_16x16x32_bf16(aR[it], qB[pt], c, 0, 0, 0);
                    acc[it][pt] = c;
                }
            }
        }

        // ---- drain accs to S overlay (r9-verified mapping) ----
        __syncthreads();   // all waves' previous-round scan reads done
#pragma unroll
        for (int it = 0; it < 4; ++it) {
#pragma unroll
            for (int pt = 0; pt < 2; ++pt) {
                int row = (ig << 6) + (it << 4) + (lh << 2);   // + reg
                int col = (pg << 5) + (pt << 4) + l15;
                float* sp = ldsf + row * SSTR + col;
                sp[0 * SSTR] = acc[it][pt][0];
                sp[1 * SSTR] = acc[it][pt][1];
                sp[2 * SSTR] = acc[it][pt][2];
                sp[3 * SSTR] = acc[it][pt][3];
            }
        }
        __syncthreads();

        // ---- scan sweep 1: max + guarded top-10 insert ----
        float mloc = rm;
#pragma unroll 4
        for (int jj = 0; jj < 32; ++jj) {
            int   il = (g << 5) + jj;
            float v  = ldsf[il * SSTR + qp];
            mloc = fmaxf(mloc, v);
            if (v > tv[TK - 1]) {
                int   id = r * RIT + il;
                float cv = v; int ci = id;
#pragma unroll
                for (int q = 0; q < TK; ++q) {
                    bool  gt = cv > tv[q];
                    float nv = gt ? tv[q]  : cv;
                    int   ni = gt ? tix[q] : ci;
                    tv[q]  = gt ? cv : tv[q];
                    tix[q] = gt ? ci : tix[q];
                    cv = nv; ci = ni;
                }
            }
        }
        rs *= __expf(rm - mloc);
        rm = mloc;
#pragma unroll 4
        for (int jj = 0; jj < 32; ++jj) {
            int   il = (g << 5) + jj;
            float v  = ldsf[il * SSTR + qp];
            rs += __expf(v - rm);
        }
    }
#undef ALOAD

    // ---- dump partials, merge, double softmax, epilogue (r9-verified) ----
    __syncthreads();
    {
#pragma unroll
        for (int q = 0; q < TK; ++q) {
            ldsf[MV_F + (qp * 8 + g) * TK + q] = tv[q];
            ldsf[MI_F + (qp * 8 + g) * TK + q] = __int_as_float(tix[q]);
        }
        ldsf[MM_F + qp * 8 + g] = rm;
        ldsf[MS_F + qp * 8 + g] = rs;
    }
    __syncthreads();

    if (t < 64) {
        const int p = t;
        float gm[8], gs[8];
#pragma unroll
        for (int G = 0; G < 8; ++G) {
            gm[G] = ldsf[MM_F + p * 8 + G];
            gs[G] = ldsf[MS_F + p * 8 + G];
        }
        float mstar = gm[0];
#pragma unroll
        for (int G = 1; G < 8; ++G) mstar = fmaxf(mstar, gm[G]);
        float Z = 0.0f;
#pragma unroll
        for (int G = 0; G < 8; ++G) Z += gs[G] * __expf(gm[G] - mstar);

        int h0=0,h1=0,h2=0,h3=0,h4=0,h5=0,h6=0,h7=0;
        float ov[TK]; int oi[TK];
#pragma unroll
        for (int o = 0; o < TK; ++o) {
            float bv = -INFINITY; int bi = 0x7fffffff; int bg = 0;
#define SEL(G, HG)                                                               \
            {                                                                    \
                float v  = ldsf[MV_F + (p * 8 + G) * TK + (HG)];                 \
                int   id = __float_as_int(ldsf[MI_F + (p * 8 + G) * TK + (HG)]); \
                if (v > bv || (v == bv && id < bi)) { bv = v; bi = id; bg = G; } \
            }
            SEL(0, h0) SEL(1, h1) SEL(2, h2) SEL(3, h3)
            SEL(4, h4) SEL(5, h5) SEL(6, h6) SEL(7, h7)
#undef SEL
            ov[o] = bv; oi[o] = bi;
            h0 += (bg == 0); h1 += (bg == 1); h2 += (bg == 2); h3 += (bg == 3);
            h4 += (bg == 4); h5 += (bg == 5); h6 += (bg == 6); h7 += (bg == 7);
        }
        float pv[TK];
#pragma unroll
        for (int o = 0; o < TK; ++o) pv[o] = __expf(ov[o] - mstar) / Z;
        float pmax = pv[0];
        float wgt[TK]; float W = 0.0f;
#pragma unroll
        for (int o = 0; o < TK; ++o) { wgt[o] = __expf(pv[o] - pmax); W += wgt[o]; }
#pragma unroll
        for (int o = 0; o < TK; ++o) {
            ldsf[WB_F + p * TK + o] = wgt[o] / W;
            ldsf[IB_F + p * TK + o] = __int_as_float(oi[o]);
        }
    }
    __syncthreads();

    {
        const int ep = t & 63, cg = t >> 6;
        float wr[TK]; const float* rows[TK];
#pragma unroll
        for (int o = 0; o < TK; ++o) {
            wr[o]   = ldsf[WB_F + ep * TK + o];
            rows[o] = mp + (size_t)__float_as_int(ldsf[IB_F + ep * TK + o]) * DIMC;
        }
        float* obase = ob + n0 + ep;
#pragma unroll 4
        for (int cc = 0; cc < 16; ++cc) {
            int c = cg * 64 + cc * 4;
            f4 a = {0.0f, 0.0f, 0.0f, 0.0f};
#pragma unroll
            for (int o = 0; o < TK; ++o) {
                f4 rv = *(const f4*)(rows[o] + c);
#pragma unroll
                for (int z = 0; z < 4; ++z) a[z] = fmaf(wr[o], rv[z], a[z]);
            }
#pragma unroll
            for (int z = 0; z < 4; ++z) obase[(size_t)(c + z) * 1024] = a[z];
        }
    }
}

// -------- fallback: r9 kernel verbatim (used when ws too small) --------
__global__ __launch_bounds__(TPB, 4)
void memorize_fb(const float* __restrict__ x0, const float* __restrict__ x1,
                 const float* __restrict__ mp, const u16* __restrict__ ws,
                 float* __restrict__ out)
{
    extern __shared__ char ldsb[];
    float* ldsf = (float*)ldsb;

    const int t    = threadIdx.x;
    const int lane = t & 63;
    const int w    = t >> 6;
    const int blk  = blockIdx.x;
    const int img  = blk >> 4;
    const int n0   = (blk & 15) * PXB;
    const int b    = img & 15;

    const float* x  = (img < 16) ? x0 : x1;
    const float* xb = x + (size_t)b * (DIMC * 1024);
    float* ob = out + (img < 16 ? (size_t)0 : (size_t)16 * DIMC * 1024)
                    + (size_t)b * (DIMC * 1024);

    const int l15 = lane & 15;
    const int lh  = lane >> 4;
    const int ksw = lh ^ KSWZ(l15);
    const int ig  = w >> 1;
    const int pg  = w & 1;
    const int qp = t & 63;
    const int g  = t >> 6;

    float tv[TK]; int tix[TK];
#pragma unroll
    for (int q = 0; q < TK; ++q) { tv[q] = -INFINITY; tix[q] = 0x7fffffff; }
    float rm = -INFINITY, rs = 0.0f;

    const int scl  = t & 31;
    const int spx  = (t >> 5) << 2;
    const int spos = (((scl >> 2) & 3) << 3) + ((scl >> 4) << 2) + (scl & 3);
    const int sslot = spos >> 3;
    const int soff  = (spos & 7) << 1;

    const u16* aw = ws + (size_t)lane * 8 + (size_t)(ig * 4) * 8192;
    const int qfb = (pg << 11) + (l15 << 6) + (ksw << 4);

#define STAGE_Q(S, BUF)                                                        \
    {                                                                          \
        const float* src = xb + (size_t)(((S) << 5) + scl) * 1024 + n0 + spx;  \
        f4 v = *(const f4*)src;                                                \
        _Pragma("unroll")                                                      \
        for (int e = 0; e < 4; ++e) {                                          \
            int px = spx + e;                                                  \
            u16 h, bb, rr; split3(v[e], h, bb, rr);                            \
            int ro = (BUF) * QB_SZ + (px << 6)                                 \
                   + (((sslot ^ KSWZ(px)) << 4) | soff);                       \
            *(u16*)(ldsb + ro)            = h;                                 \
            *(u16*)(ldsb + ro + Q_PL)     = bb;                                \
            *(u16*)(ldsb + ro + 2 * Q_PL) = rr;                                \
        }                                                                      \
    }

#define ALOADF(IT, S)                                                          \
    {                                                                          \
        const u16* ap = ar + ((size_t)(IT) << 13) + ((S) << 9);                \
        aH[IT] = *(const f16x8*) (ap + 0 * WSP);                               \
        aB[IT] = *(const bf16x8*)(ap + 1 * WSP);                               \
        aR[IT] = *(const bf16x8*)(ap + 2 * WSP);                               \
    }

#pragma unroll 1
    for (int r = 0; r < NRND; ++r) {
        const u16* ar = aw + ((size_t)r << 17);
        f4 acc[4][2];
#pragma unroll
        for (int it = 0; it < 4; ++it)
#pragma unroll
            for (int pt = 0; pt < 2; ++pt) acc[it][pt] = (f4){0.f, 0.f, 0.f, 0.f};

        __syncthreads();
        STAGE_Q(0, 0)
        __syncthreads();

#pragma unroll 1
        for (int s = 0; s < NSLICE; ++s) {
            const int cur = s & 1;
            f16x8 aH[4]; bf16x8 aB[4], aR[4];
            ALOADF(0, s)
            ALOADF(1, s)
            if (s + 1 < NSLICE) STAGE_Q(s + 1, cur ^ 1)

            const char* qc = ldsb + cur * QB_SZ + qfb;
            f16x8 qH[2]; bf16x8 qB[2], qR[2];
#pragma unroll
            for (int pt = 0; pt < 2; ++pt) {
                qH[pt] = *(const f16x8*) (qc + 0 * Q_PL + pt * 1024);
                qB[pt] = *(const bf16x8*)(qc + 1 * Q_PL + pt * 1024);
                qR[pt] = *(const bf16x8*)(qc + 2 * Q_PL + pt * 1024);
            }
#pragma unroll
            for (int it = 0; it < 4; ++it) {
                if (it < 2) ALOADF(it + 2, s)
#pragma unroll
                for (int pt = 0; pt < 2; ++pt) {
                    f4 c = acc[it][pt];
                    c = __builtin_amdgcn_mfma_f32_16x16x32_f16 (aH[it], qH[pt], c, 0, 0, 0);
                    c = __builtin_amdgcn_mfma_f32_16x16x32_bf16(aB[it], qR[pt], c, 0, 0, 0);
                    c = __builtin_amdgcn_mfma_f32_16x16x32_bf16(aR[it], qB[pt], c, 0, 0, 0);
                    acc[it][pt] = c;
                }
            }
            __syncthreads();
        }

#pragma unroll
        for (int it = 0; it < 4; ++it) {
#pragma unroll
            for (int pt = 0; pt < 2; ++pt) {
                int row = (ig << 6) + (it << 4) + (lh << 2);
                int col = (pg << 5) + (pt << 4) + l15;
                float* sp = ldsf + row * SSTR + col;
                sp[0 * SSTR] = acc[it][pt][0];
                sp[1 * SSTR] = acc[it][pt][1];
                sp[2 * SSTR] = acc[it][pt][2];
                sp[3 * SSTR] = acc[it][pt][3];
            }
        }
        __syncthreads();

        float mloc = rm;
#pragma unroll 4
        for (int jj = 0; jj < 32; ++jj) {
            int   il = (g << 5) + jj;
            float v  = ldsf[il * SSTR + qp];
            mloc = fmaxf(mloc, v);
            if (v > tv[TK - 1]) {
                int   id = r * RIT + il;
                float cv = v; int ci = id;
#pragma unroll
                for (int q = 0; q < TK; ++q) {
                    bool  gt = cv > tv[q];
                    float nv = gt ? tv[q]  : cv;
                    int   ni = gt ? tix[q] : ci;
                    tv[q]  = gt ? cv : tv[q];
                    tix[q] = gt ? ci : tix[q];
                    cv = nv; ci = ni;
                }
            }
        }
        rs *= __expf(rm - mloc);
        rm = mloc;
#pragma unroll 4
        for (int jj = 0; jj < 32; ++jj) {
            int   il = (g << 5) + jj;
            float v  = ldsf[il * SSTR + qp];
            rs += __expf(v - rm);
        }
    }
#undef STAGE_Q
#undef ALOADF

    __syncthreads();
    {
#pragma unroll
        for (int q = 0; q < TK; ++q) {
            ldsf[MV_F + (qp * 8 + g) * TK + q] = tv[q];
            ldsf[MI_F + (qp * 8 + g) * TK + q] = __int_as_float(tix[q]);
        }
        ldsf[MM_F + qp * 8 + g] = rm;
        ldsf[MS_F + qp * 8 + g] = rs;
    }
    __syncthreads();

    if (t < 64) {
        const int p = t;
        float gm[8], gs[8];
#pragma unroll
        for (int G = 0; G < 8; ++G) {
            gm[G] = ldsf[MM_F + p * 8 + G];
            gs[G] = ldsf[MS_F + p * 8 + G];
        }
        float mstar = gm[0];
#pragma unroll
        for (int G = 1; G < 8; ++G) mstar = fmaxf(mstar, gm[G]);
        float Z = 0.0f;
#pragma unroll
        for (int G = 0; G < 8; ++G) Z += gs[G] * __expf(gm[G] - mstar);

        int h0=0,h1=0,h2=0,h3=0,h4=0,h5=0,h6=0,h7=0;
        float ov[TK]; int oi[TK];
#pragma unroll
        for (int o = 0; o < TK; ++o) {
            float bv = -INFINITY; int bi = 0x7fffffff; int bg = 0;
#define SEL(G, HG)                                                               \
            {                                                                    \
                float v  = ldsf[MV_F + (p * 8 + G) * TK + (HG)];                 \
                int   id = __float_as_int(ldsf[MI_F + (p * 8 + G) * TK + (HG)]); \
                if (v > bv || (v == bv && id < bi)) { bv = v; bi = id; bg = G; } \
            }
            SEL(0, h0) SEL(1, h1) SEL(2, h2) SEL(3, h3)
            SEL(4, h4) SEL(5, h5) SEL(6, h6) SEL(7, h7)
#undef SEL
            ov[o] = bv; oi[o] = bi;
            h0 += (bg == 0); h1 += (bg == 1); h2 += (bg == 2); h3 += (bg == 3);
            h4 += (bg == 4); h5 += (bg == 5); h6 += (bg == 6); h7 += (bg == 7);
        }
        float pv[TK];
#pragma unroll
        for (int o = 0; o < TK; ++o) pv[o] = __expf(ov[o] - mstar) / Z;
        float pmax = pv[0];
        float wgt[TK]; float W = 0.0f;
#pragma unroll
        for (int o = 0; o < TK; ++o) { wgt[o] = __expf(pv[o] - pmax); W += wgt[o]; }
#pragma unroll
        for (int o = 0; o < TK; ++o) {
            ldsf[WB_F + p * TK + o] = wgt[o] / W;
            ldsf[IB_F + p * TK + o] = __int_as_float(oi[o]);
        }
    }
    __syncthreads();

    {
        const int ep = t & 63, cg = t >> 6;
        float wr[TK]; const float* rows[TK];
#pragma unroll
        for (int o = 0; o < TK; ++o) {
            wr[o]   = ldsf[WB_F + ep * TK + o];
            rows[o] = mp + (size_t)__float_as_int(ldsf[IB_F + ep * TK + o]) * DIMC;
        }
        float* obase = ob + n0 + ep;
#pragma unroll 4
        for (int cc = 0; cc < 16; ++cc) {
            int c = cg * 64 + cc * 4;
            f4 a = {0.0f, 0.0f, 0.0f, 0.0f};
#pragma unroll
            for (int o = 0; o < TK; ++o) {
                f4 rv = *(const f4*)(rows[o] + c);
#pragma unroll
                for (int z = 0; z < 4; ++z) a[z] = fmaf(wr[o], rv[z], a[z]);
            }
#pragma unroll
            for (int z = 0; z < 4; ++z) obase[(size_t)(c + z) * 1024] = a[z];
        }
    }
}

extern "C" void kernel_launch(void* const* d_in, const int* in_sizes, int n_in,
                              void* d_out, int out_size, void* d_ws, size_t ws_size,
                              hipStream_t stream) {
    const float* x0  = (const float*)d_in[0];
    const float* x1  = (const float*)d_in[1];
    const float* mpl = (const float*)d_in[2];
    float* out = (float*)d_out;
    u16* ws = (u16*)d_ws;

    const size_t ws_need = ((size_t)QWS_OFF + 3ull * (size_t)XWSP) * 2ull; // ~107 MB

    preconv_kernel<<<dim3(1024), dim3(256), 0, stream>>>(mpl, ws);
    if (ws_size >= ws_need) {
        preconv_x_kernel<<<dim3(16384), dim3(256), 0, stream>>>(x0, x1, ws);
        memorize_direct<<<dim3(512), dim3(TPB), 0, stream>>>(mpl, ws, out);
    } else {
        memorize_fb<<<dim3(512), dim3(TPB), LDS_BYTES, stream>>>(x0, x1, mpl, ws, out);
    }
}